// Round 1
// baseline (219.437 us; speedup 1.0000x reference)
//
#include <hip/hip_runtime.h>
#include <stdint.h>

typedef unsigned short u16;
typedef __attribute__((ext_vector_type(8))) short short8_t;
typedef __attribute__((ext_vector_type(4))) float f32x4;

#define D_DIM 512
#define K_CL  256
#define BM    128
#define BK    64
#define NSTEP (D_DIM / BK)   // 8

__device__ __forceinline__ u16 f2bf(float f) {
  union { float f; uint32_t u; } v; v.f = f;
  uint32_t r = v.u + 0x7fffu + ((v.u >> 16) & 1u);  // RNE
  return (u16)(r >> 16);
}

__device__ __forceinline__ short8_t pack8(float4 f0, float4 f1) {
  union { u16 u[8]; short8_t v; } pk;
  pk.u[0] = f2bf(f0.x); pk.u[1] = f2bf(f0.y);
  pk.u[2] = f2bf(f0.z); pk.u[3] = f2bf(f0.w);
  pk.u[4] = f2bf(f1.x); pk.u[5] = f2bf(f1.y);
  pk.u[6] = f2bf(f1.z); pk.u[7] = f2bf(f1.w);
  return pk.v;
}

// prep: clusters fp32 [256][512] -> bf16 cb [256][512] + csq[256] (fp32 norms)
__global__ void prep_kernel(const float* __restrict__ clusters,
                            u16* __restrict__ cb, float* __restrict__ csq) {
  int k = blockIdx.x;
  int t = threadIdx.x;  // 128 threads, 4 floats each
  float4 f = ((const float4*)(clusters + (size_t)k * D_DIM))[t];
  ushort4 u;
  u.x = f2bf(f.x); u.y = f2bf(f.y); u.z = f2bf(f.z); u.w = f2bf(f.w);
  ((ushort4*)(cb + (size_t)k * D_DIM))[t] = u;
  float s = f.x*f.x + f.y*f.y + f.z*f.z + f.w*f.w;
  #pragma unroll
  for (int m = 1; m < 64; m <<= 1) s += __shfl_xor(s, m, 64);
  __shared__ float part[2];
  if ((t & 63) == 0) part[t >> 6] = s;
  __syncthreads();
  if (t == 0) csq[k] = part[0] + part[1];
}

// main: 8 waves, each wave owns 16 rows x all 256 cols.
// A: global -> registers -> bf16 frags (no LDS). B: LDS, BK=64 double-buffer,
// XOR-swizzled via pre-swizzled global source (global_load_lds dest stays linear).
__global__ __launch_bounds__(512, 4)
void cluster_kernel(const float* __restrict__ x,
                    const u16* __restrict__ cb,
                    const float* __restrict__ csq,
                    float* __restrict__ out) {
  __shared__ u16 lB[2 * K_CL * BK];   // 64 KB double buffer

  const int tid  = threadIdx.x;
  const int lane = tid & 63;
  const int w    = tid >> 6;          // wave 0..7 -> row stripe
  const int l16  = lane & 15;
  const int quad = lane >> 4;
  const int row0 = blockIdx.x * BM;

  // ---- A: lane covers row (w*16+l16), k-slices quad*8 (+0 / +32) ----
  const int arow = row0 + w * 16 + l16;
  const float4* xg = (const float4*)(x + (size_t)arow * D_DIM + quad * 8);

  // ---- B staging sources, pre-swizzled: dest o = i*8192 + tid*16 (linear),
  // n = o>>7, kb = o&127, source kb' = kb ^ ((n&7)<<4) ----
  const int o0   = tid * 16;                 // i=0 chunk
  const int n0   = o0 >> 7;
  const int skb0 = (o0 & 127) ^ ((n0 & 7) << 4);
  const int o1   = 8192 + tid * 16;          // i=1 chunk
  const int n1   = o1 >> 7;
  const int skb1 = (o1 & 127) ^ ((n1 & 7) << 4);
  const u16* sp0 = cb + (size_t)n0 * D_DIM + (skb0 >> 1);
  const u16* sp1 = cb + (size_t)n1 * D_DIM + (skb1 >> 1);
  // i=2,3 are the same pattern 128 cluster-rows later: +128*512 u16

  // ---- swizzled ds_read byte offsets (per lane) ----
  const int c3 = (l16 & 3) << 4;
  const int h  = (l16 & 4) << 4;
  const int p  = l16 * 128 + ((quad * 16) ^ c3);
  const int p0 = p + h;           // kk32 = 0
  const int p1 = p + (h ^ 64);    // kk32 = 1

  f32x4 acc[16];
  #pragma unroll
  for (int i = 0; i < 16; ++i) acc[i] = (f32x4){0.f, 0.f, 0.f, 0.f};

  // ---- prologue: stage step 0 into buf0, prefetch A step 0 ----
  {
    char* dstb = (char*)lB + tid * 16;
    __builtin_amdgcn_global_load_lds((const __attribute__((address_space(1))) void*)sp0,
        (__attribute__((address_space(3))) void*)(dstb),          16, 0, 0);
    __builtin_amdgcn_global_load_lds((const __attribute__((address_space(1))) void*)sp1,
        (__attribute__((address_space(3))) void*)(dstb + 8192),   16, 0, 0);
    __builtin_amdgcn_global_load_lds((const __attribute__((address_space(1))) void*)(sp0 + 65536),
        (__attribute__((address_space(3))) void*)(dstb + 16384),  16, 0, 0);
    __builtin_amdgcn_global_load_lds((const __attribute__((address_space(1))) void*)(sp1 + 65536),
        (__attribute__((address_space(3))) void*)(dstb + 24576),  16, 0, 0);
  }
  float4 a0 = xg[0], a1 = xg[1], a2 = xg[8], a3 = xg[9];

  float sq = 0.f;

  for (int step = 0; step < NSTEP; ++step) {
    __syncthreads();   // buf[step&1] staged; buf[step&1 ^ 1] free to overwrite

    // convert current A regs -> frags, accumulate ||x||^2 from fp32
    sq += a0.x*a0.x + a0.y*a0.y + a0.z*a0.z + a0.w*a0.w
        + a1.x*a1.x + a1.y*a1.y + a1.z*a1.z + a1.w*a1.w
        + a2.x*a2.x + a2.y*a2.y + a2.z*a2.z + a2.w*a2.w
        + a3.x*a3.x + a3.y*a3.y + a3.z*a3.z + a3.w*a3.w;
    short8_t aF0 = pack8(a0, a1);
    short8_t aF1 = pack8(a2, a3);

    if (step + 1 < NSTEP) {
      // prefetch next A (HBM latency hides under ds_read + MFMA below)
      xg += 16;
      a0 = xg[0]; a1 = xg[1]; a2 = xg[8]; a3 = xg[9];
      // stage next B into the other buffer
      sp0 += BK; sp1 += BK;
      char* dstb = (char*)lB + (((step + 1) & 1) << 15) + tid * 16;
      __builtin_amdgcn_global_load_lds((const __attribute__((address_space(1))) void*)sp0,
          (__attribute__((address_space(3))) void*)(dstb),          16, 0, 0);
      __builtin_amdgcn_global_load_lds((const __attribute__((address_space(1))) void*)sp1,
          (__attribute__((address_space(3))) void*)(dstb + 8192),   16, 0, 0);
      __builtin_amdgcn_global_load_lds((const __attribute__((address_space(1))) void*)(sp0 + 65536),
          (__attribute__((address_space(3))) void*)(dstb + 16384),  16, 0, 0);
      __builtin_amdgcn_global_load_lds((const __attribute__((address_space(1))) void*)(sp1 + 65536),
          (__attribute__((address_space(3))) void*)(dstb + 24576),  16, 0, 0);
    }

    // B frags from swizzled LDS + 32 MFMA (16 ni-blocks x K=64)
    const char* pb = (const char*)lB + ((step & 1) << 15);
    const short8_t* q0 = (const short8_t*)(pb + p0);
    const short8_t* q1 = (const short8_t*)(pb + p1);
    #pragma unroll
    for (int ni = 0; ni < 16; ++ni) {
      short8_t b0 = q0[ni * 128];   // ni*2048 bytes
      short8_t b1 = q1[ni * 128];
      acc[ni] = __builtin_amdgcn_mfma_f32_16x16x32_bf16(aF0, b0, acc[ni], 0, 0, 0);
      acc[ni] = __builtin_amdgcn_mfma_f32_16x16x32_bf16(aF1, b1, acc[ni], 0, 0, 0);
    }
  }

  // ---- epilogue (wave-local: no barriers, no LDS) ----
  // full row norm for row (w*16 + l16): sum partials across quads
  sq += __shfl_xor(sq, 16, 64);
  sq += __shfl_xor(sq, 32, 64);
  // C layout: row = quad*4 + v, col = ni*16 + l16 -> need sq of rows quad*4+v
  float xs[4];
  #pragma unroll
  for (int v = 0; v < 4; ++v)
    xs[v] = __shfl(sq, quad * 4 + v, 64);

  float cs[16];
  #pragma unroll
  for (int ni = 0; ni < 16; ++ni) cs[ni] = csq[ni * 16 + l16];

  float rs[4] = {0.f, 0.f, 0.f, 0.f};
  #pragma unroll
  for (int ni = 0; ni < 16; ++ni) {
    #pragma unroll
    for (int v = 0; v < 4; ++v) {
      float d = xs[v] + cs[ni] - 2.0f * acc[ni][v];
      d = fmaxf(d, 0.f);
      float qv = __builtin_amdgcn_rcpf(1.0f + d);   // alpha=1: (1+d^2)^-1
      acc[ni][v] = qv;
      rs[v] += qv;
    }
  }
  #pragma unroll
  for (int v = 0; v < 4; ++v) {
    rs[v] += __shfl_xor(rs[v], 1, 64);
    rs[v] += __shfl_xor(rs[v], 2, 64);
    rs[v] += __shfl_xor(rs[v], 4, 64);
    rs[v] += __shfl_xor(rs[v], 8, 64);
    rs[v] = __builtin_amdgcn_rcpf(rs[v]);
  }
  #pragma unroll
  for (int v = 0; v < 4; ++v) {
    float* orow = out + (size_t)(row0 + w * 16 + quad * 4 + v) * K_CL;
    #pragma unroll
    for (int ni = 0; ni < 16; ++ni)
      orow[ni * 16 + l16] = acc[ni][v] * rs[v];
  }
}

extern "C" void kernel_launch(void* const* d_in, const int* in_sizes, int n_in,
                              void* d_out, int out_size, void* d_ws, size_t ws_size,
                              hipStream_t stream) {
  const float* x        = (const float*)d_in[0];
  const float* clusters = (const float*)d_in[1];
  float* out = (float*)d_out;
  const int N = in_sizes[0] / D_DIM;   // 65536

  u16*   cb  = (u16*)d_ws;                                    // 256*512*2 = 256 KB
  float* csq = (float*)((char*)d_ws + (size_t)K_CL * D_DIM * sizeof(u16));

  prep_kernel<<<K_CL, 128, 0, stream>>>(clusters, cb, csq);
  cluster_kernel<<<N / BM, 512, 0, stream>>>(x, cb, csq, out);
}